// Round 6
// baseline (223.213 us; speedup 1.0000x reference)
//
#include <hip/hip_runtime.h>

typedef __bf16 bf16x4 __attribute__((ext_vector_type(4)));
typedef __bf16 bf16x8 __attribute__((ext_vector_type(8)));
typedef float  f32x4  __attribute__((ext_vector_type(4)));

struct KArgs {
    const float* x[6];
    const float* W[6];
    const float* b[6];
    float*       out[6];
    int nrows[6];
    int blk0[7];   // cumulative block offsets per type
};

// lgkm-only barrier: LDS visibility across waves WITHOUT draining global
// store-acks / keeping the vmem queue (see R6 theory; hazards re-derived).
__device__ __forceinline__ void lds_barrier() {
    asm volatile("s_waitcnt lgkmcnt(0)\n\ts_barrier" ::: "memory");
}

// Double-buffered LDS pipeline, ONE lgkm-barrier per chunk.
//   iter n: issue loads(n+1)->regs | ds_read buf[cur] -> MFMA -> store(n)
//           | cvt+ds_write buf[cur^1] (counted vmcnt waits loads only)
//           | lds_barrier()
// Every FIN stages 16 KB/chunk: ROWS = 8192/FIN (128/64/32 rows).
// A = W (M = out col, bf16 regs), B = x (N = x row, LDS XOR-swizzled).
// D lane map (m89): col(l15) = x-row, row(lq*4+r) = out col -> float4 stores.
template<int FIN>
__device__ __forceinline__ void run_type(
    const float* __restrict__ x, const float* __restrict__ W,
    const float* __restrict__ bias, float* __restrict__ out,
    int nrows, int c0, int c1, __bf16* __restrict__ lds)
{
    constexpr int ROWS = 8192 / FIN;   // rows per chunk
    constexpr int NC   = FIN / 32;     // k-fragments
    constexpr int MT   = ROWS / 16;    // m-tiles per chunk
    constexpr int S    = FIN * 2;      // LDS row stride, bytes
    constexpr int QPR  = FIN / 4;      // float4 per row (power of 2)

    const int tid     = threadIdx.x;
    const int lane    = tid & 63;
    const int wave    = tid >> 6;
    const int l15     = lane & 15;
    const int lq      = lane >> 4;
    const int colbase = wave * 32;     // each wave owns 32 output cols

    // ---- W fragments (A operand), fp32 -> bf16 once per block
    bf16x8 Wf[NC][2];
    f32x4  bv[2];
    #pragma unroll
    for (int t = 0; t < 2; ++t) {
        const int o = colbase + t * 16 + l15;          // out col = W row
        #pragma unroll
        for (int c = 0; c < NC; ++c) {
            const f32x4 w0 = *(const f32x4*)(W + (size_t)o * FIN + c * 32 + lq * 8);
            const f32x4 w1 = *(const f32x4*)(W + (size_t)o * FIN + c * 32 + lq * 8 + 4);
            bf16x8 fr;
            fr[0] = (__bf16)w0[0]; fr[1] = (__bf16)w0[1];
            fr[2] = (__bf16)w0[2]; fr[3] = (__bf16)w0[3];
            fr[4] = (__bf16)w1[0]; fr[5] = (__bf16)w1[1];
            fr[6] = (__bf16)w1[2]; fr[7] = (__bf16)w1[3];
            Wf[c][t] = fr;
        }
        bv[t] = *(const f32x4*)(bias + colbase + t * 16 + lq * 4);
    }

    f32x4 fbuf[8];   // in-flight fp32 x data for the NEXT chunk

    auto issue = [&](int chunk) {       // global -> regs, no wait
        #pragma unroll
        for (int i = 0; i < 8; ++i) {
            const int u  = tid + i * 256;
            const int r  = u / QPR;
            const int kq = u % QPR;
            int gr = chunk * ROWS + r;
            if (gr >= nrows) gr = nrows - 1;           // clamp; stores guarded
            fbuf[i] = __builtin_nontemporal_load(
                (const f32x4*)(x + (size_t)gr * FIN + kq * 4));
        }
    };
    auto commit = [&](int b) {          // cvt + ds_write (counted vmcnt on loads)
        __bf16* dst = lds + b * 8192;
        #pragma unroll
        for (int i = 0; i < 8; ++i) {
            const int u  = tid + i * 256;
            const int r  = u / QPR;
            const int kq = u % QPR;
            bf16x4 q;
            q[0] = (__bf16)fbuf[i][0]; q[1] = (__bf16)fbuf[i][1];
            q[2] = (__bf16)fbuf[i][2]; q[3] = (__bf16)fbuf[i][3];
            const int byte = (r * S + kq * 8) ^ ((r & 7) << 4);
            *(bf16x4*)((char*)dst + byte) = q;
        }
    };

    issue(c0);
    commit(0);
    lds_barrier();

    int cur = 0;
    for (int n = c0; n < c1; ++n) {
        const bool more = (n + 1 < c1);
        if (more) issue(n + 1);         // prefetch; consumed after compute

        const __bf16* src = lds + cur * 8192;
        #pragma unroll
        for (int mt = 0; mt < MT; ++mt) {
            const int row = mt * 16 + l15;
            f32x4 acc0 = {0.f, 0.f, 0.f, 0.f};
            f32x4 acc1 = {0.f, 0.f, 0.f, 0.f};
            #pragma unroll
            for (int c = 0; c < NC; ++c) {
                const int byte = (row * S + c * 64 + lq * 16) ^ ((row & 7) << 4);
                const bf16x8 xf = *(const bf16x8*)((const char*)src + byte);
                acc0 = __builtin_amdgcn_mfma_f32_16x16x32_bf16(Wf[c][0], xf, acc0, 0, 0, 0);
                acc1 = __builtin_amdgcn_mfma_f32_16x16x32_bf16(Wf[c][1], xf, acc1, 0, 0, 0);
            }
            const int xrow = n * ROWS + mt * 16 + l15;
            if (xrow < nrows) {
                float* op = out + (size_t)xrow * 128 + colbase;
                __builtin_nontemporal_store(acc0 + bv[0], (f32x4*)(op + lq * 4));
                __builtin_nontemporal_store(acc1 + bv[1], (f32x4*)(op + 16 + lq * 4));
            }
        }

        if (more) commit(cur ^ 1);
        lds_barrier();
        cur ^= 1;
    }
}

__global__ __launch_bounds__(256, 4) void hetero_fused_kern(KArgs A)
{
    __shared__ __bf16 lds[2 * 8192];   // 32 KiB: double buffer

    int ty = 0;
    const int bid = blockIdx.x;
    while (ty < 5 && bid >= A.blk0[ty + 1]) ++ty;
    const int lb = bid - A.blk0[ty];
    const int nb = A.blk0[ty + 1] - A.blk0[ty];

    const int nrows  = A.nrows[ty];
    const int ROWS   = (ty == 1) ? 32 : ((ty == 2 || ty == 4) ? 128 : 64);
    const int chunks = (nrows + ROWS - 1) / ROWS;
    const int c0 = (int)(((long)chunks * lb) / nb);
    const int c1 = (int)(((long)chunks * (lb + 1)) / nb);
    if (c0 >= c1) return;

    switch (ty) {
        case 0: run_type<128>(A.x[0], A.W[0], A.b[0], A.out[0], nrows, c0, c1, lds); break;
        case 1: run_type<256>(A.x[1], A.W[1], A.b[1], A.out[1], nrows, c0, c1, lds); break;
        case 2: run_type< 64>(A.x[2], A.W[2], A.b[2], A.out[2], nrows, c0, c1, lds); break;
        case 3: run_type<128>(A.x[3], A.W[3], A.b[3], A.out[3], nrows, c0, c1, lds); break;
        case 4: run_type< 64>(A.x[4], A.W[4], A.b[4], A.out[4], nrows, c0, c1, lds); break;
        case 5: run_type<128>(A.x[5], A.W[5], A.b[5], A.out[5], nrows, c0, c1, lds); break;
    }
}

extern "C" void kernel_launch(void* const* d_in, const int* in_sizes, int n_in,
                              void* d_out, int out_size, void* d_ws, size_t ws_size,
                              hipStream_t stream)
{
    float* out = (float*)d_out;
    KArgs A;
    // setup_inputs order: (x,W,b) per type:
    // 0 author(100000,128) 1 paper(250000,256) 2 venue(25000,64)
    // 3 institution(50000,128) 4 field(75000,64) 5 term(150000,128)
    const int  nrows[6] = {100000, 250000, 25000, 50000, 75000, 150000};
    const long ooff[6]  = {0L, 12800000L, 44800000L, 48000000L, 54400000L, 64000000L};
    // 2048 blocks (R2's winning granularity); bytes-proportional split
    const int  blk0[7]  = {0, 273, 1297, 1348, 1485, 1639, 2048};
    for (int t = 0; t < 6; ++t) {
        A.x[t]     = (const float*)d_in[3 * t + 0];
        A.W[t]     = (const float*)d_in[3 * t + 1];
        A.b[t]     = (const float*)d_in[3 * t + 2];
        A.out[t]   = out + ooff[t];
        A.nrows[t] = nrows[t];
    }
    for (int i = 0; i < 7; ++i) A.blk0[i] = blk0[i];

    hetero_fused_kern<<<2048, 256, 0, stream>>>(A);
}

// Round 7
// 171.863 us; speedup vs baseline: 1.2988x; 1.2988x over previous
//
#include <hip/hip_runtime.h>

typedef __bf16 bf16x4 __attribute__((ext_vector_type(4)));
typedef __bf16 bf16x8 __attribute__((ext_vector_type(8)));
typedef float  f32x4  __attribute__((ext_vector_type(4)));

struct KArgs {
    const float* x[6];
    const float* W[6];
    const float* b[6];
    float*       out[6];
    int nrows[6];
    int blk0[7];   // cumulative block offsets per type
};

// lgkm-only barrier: LDS visibility across waves WITHOUT draining global
// store-acks (stores have no cross-wave consumer; loads are vmcnt-counted
// by the compiler before their use in commit()).
__device__ __forceinline__ void lds_barrier() {
    asm volatile("s_waitcnt lgkmcnt(0)\n\ts_barrier" ::: "memory");
}

// Double-buffered LDS pipeline, ONE lgkm-barrier per chunk.
//   iter n: issue loads(n+1)->regs | ds_read buf[cur] -> MFMA -> store(n)
//           | cvt+ds_write buf[cur^1] | lds_barrier()
// Every FIN stages 8 KB/chunk: ROWS = 4096/FIN (64/32/16 rows) ->
// fbuf = 16 VGPRs, paper path ~110 VGPRs total (no spill at cap 128).
// A = W (M = out col, bf16 regs), B = x (N = x row, LDS XOR-swizzled).
// D lane map (m89): col(l15) = x-row, row(lq*4+r) = out col -> float4 stores.
template<int FIN>
__device__ __forceinline__ void run_type(
    const float* __restrict__ x, const float* __restrict__ W,
    const float* __restrict__ bias, float* __restrict__ out,
    int nrows, int c0, int c1, __bf16* __restrict__ lds)
{
    constexpr int ROWS = 4096 / FIN;   // rows per chunk
    constexpr int NC   = FIN / 32;     // k-fragments
    constexpr int MT   = ROWS / 16;    // m-tiles per chunk
    constexpr int S    = FIN * 2;      // LDS row stride, bytes
    constexpr int QPR  = FIN / 4;      // float4 per row (power of 2)

    const int tid     = threadIdx.x;
    const int lane    = tid & 63;
    const int wave    = tid >> 6;
    const int l15     = lane & 15;
    const int lq      = lane >> 4;
    const int colbase = wave * 32;     // each wave owns 32 output cols

    // ---- W fragments (A operand), fp32 -> bf16 once per block
    bf16x8 Wf[NC][2];
    f32x4  bv[2];
    #pragma unroll
    for (int t = 0; t < 2; ++t) {
        const int o = colbase + t * 16 + l15;          // out col = W row
        #pragma unroll
        for (int c = 0; c < NC; ++c) {
            const f32x4 w0 = *(const f32x4*)(W + (size_t)o * FIN + c * 32 + lq * 8);
            const f32x4 w1 = *(const f32x4*)(W + (size_t)o * FIN + c * 32 + lq * 8 + 4);
            bf16x8 fr;
            fr[0] = (__bf16)w0[0]; fr[1] = (__bf16)w0[1];
            fr[2] = (__bf16)w0[2]; fr[3] = (__bf16)w0[3];
            fr[4] = (__bf16)w1[0]; fr[5] = (__bf16)w1[1];
            fr[6] = (__bf16)w1[2]; fr[7] = (__bf16)w1[3];
            Wf[c][t] = fr;
        }
        bv[t] = *(const f32x4*)(bias + colbase + t * 16 + lq * 4);
    }

    f32x4 fbuf[4];   // in-flight fp32 x data for the NEXT chunk (16 VGPRs)

    auto issue = [&](int chunk) {       // global -> regs, no wait
        #pragma unroll
        for (int i = 0; i < 4; ++i) {
            const int u  = tid + i * 256;
            const int r  = u / QPR;
            const int kq = u % QPR;
            int gr = chunk * ROWS + r;
            if (gr >= nrows) gr = nrows - 1;           // clamp; stores guarded
            fbuf[i] = __builtin_nontemporal_load(
                (const f32x4*)(x + (size_t)gr * FIN + kq * 4));
        }
    };
    auto commit = [&](int b) {          // cvt + ds_write (counted vmcnt on loads)
        __bf16* dst = lds + b * 4096;
        #pragma unroll
        for (int i = 0; i < 4; ++i) {
            const int u  = tid + i * 256;
            const int r  = u / QPR;
            const int kq = u % QPR;
            bf16x4 q;
            q[0] = (__bf16)fbuf[i][0]; q[1] = (__bf16)fbuf[i][1];
            q[2] = (__bf16)fbuf[i][2]; q[3] = (__bf16)fbuf[i][3];
            const int byte = (r * S + kq * 8) ^ ((r & 7) << 4);
            *(bf16x4*)((char*)dst + byte) = q;
        }
    };

    issue(c0);
    commit(0);
    lds_barrier();

    int cur = 0;
    for (int n = c0; n < c1; ++n) {
        const bool more = (n + 1 < c1);
        if (more) issue(n + 1);         // prefetch; consumed after compute

        const __bf16* src = lds + cur * 4096;
        #pragma unroll
        for (int mt = 0; mt < MT; ++mt) {
            const int row = mt * 16 + l15;
            f32x4 acc0 = {0.f, 0.f, 0.f, 0.f};
            f32x4 acc1 = {0.f, 0.f, 0.f, 0.f};
            #pragma unroll
            for (int c = 0; c < NC; ++c) {
                const int byte = (row * S + c * 64 + lq * 16) ^ ((row & 7) << 4);
                const bf16x8 xf = *(const bf16x8*)((const char*)src + byte);
                acc0 = __builtin_amdgcn_mfma_f32_16x16x32_bf16(Wf[c][0], xf, acc0, 0, 0, 0);
                acc1 = __builtin_amdgcn_mfma_f32_16x16x32_bf16(Wf[c][1], xf, acc1, 0, 0, 0);
            }
            const int xrow = n * ROWS + mt * 16 + l15;
            if (xrow < nrows) {
                float* op = out + (size_t)xrow * 128 + colbase;
                __builtin_nontemporal_store(acc0 + bv[0], (f32x4*)(op + lq * 4));
                __builtin_nontemporal_store(acc1 + bv[1], (f32x4*)(op + 16 + lq * 4));
            }
        }

        if (more) commit(cur ^ 1);
        lds_barrier();
        cur ^= 1;
    }
}

__global__ __launch_bounds__(256, 2) void hetero_fused_kern(KArgs A)
{
    __shared__ __bf16 lds[2 * 4096];   // 16 KiB: double buffer

    int ty = 0;
    const int bid = blockIdx.x;
    while (ty < 5 && bid >= A.blk0[ty + 1]) ++ty;
    const int lb = bid - A.blk0[ty];
    const int nb = A.blk0[ty + 1] - A.blk0[ty];

    const int nrows  = A.nrows[ty];
    const int ROWS   = (ty == 1) ? 16 : ((ty == 2 || ty == 4) ? 64 : 32);
    const int chunks = (nrows + ROWS - 1) / ROWS;
    const int c0 = (int)(((long)chunks * lb) / nb);
    const int c1 = (int)(((long)chunks * (lb + 1)) / nb);
    if (c0 >= c1) return;

    switch (ty) {
        case 0: run_type<128>(A.x[0], A.W[0], A.b[0], A.out[0], nrows, c0, c1, lds); break;
        case 1: run_type<256>(A.x[1], A.W[1], A.b[1], A.out[1], nrows, c0, c1, lds); break;
        case 2: run_type< 64>(A.x[2], A.W[2], A.b[2], A.out[2], nrows, c0, c1, lds); break;
        case 3: run_type<128>(A.x[3], A.W[3], A.b[3], A.out[3], nrows, c0, c1, lds); break;
        case 4: run_type< 64>(A.x[4], A.W[4], A.b[4], A.out[4], nrows, c0, c1, lds); break;
        case 5: run_type<128>(A.x[5], A.W[5], A.b[5], A.out[5], nrows, c0, c1, lds); break;
    }
}

extern "C" void kernel_launch(void* const* d_in, const int* in_sizes, int n_in,
                              void* d_out, int out_size, void* d_ws, size_t ws_size,
                              hipStream_t stream)
{
    float* out = (float*)d_out;
    KArgs A;
    // setup_inputs order: (x,W,b) per type:
    // 0 author(100000,128) 1 paper(250000,256) 2 venue(25000,64)
    // 3 institution(50000,128) 4 field(75000,64) 5 term(150000,128)
    const int  nrows[6] = {100000, 250000, 25000, 50000, 75000, 150000};
    const long ooff[6]  = {0L, 12800000L, 44800000L, 48000000L, 54400000L, 64000000L};
    // 2048 blocks; bytes-proportional split
    const int  blk0[7]  = {0, 273, 1297, 1348, 1485, 1639, 2048};
    for (int t = 0; t < 6; ++t) {
        A.x[t]     = (const float*)d_in[3 * t + 0];
        A.W[t]     = (const float*)d_in[3 * t + 1];
        A.b[t]     = (const float*)d_in[3 * t + 2];
        A.out[t]   = out + ooff[t];
        A.nrows[t] = nrows[t];
    }
    for (int i = 0; i < 7; ++i) A.blk0[i] = blk0[i];

    hetero_fused_kern<<<2048, 256, 0, stream>>>(A);
}